// Round 6
// baseline (104.861 us; speedup 1.0000x reference)
//
#include <hip/hip_runtime.h>
#include <math.h>

#define NB 8192
#define NC 128
#define JPT 8              // j-tiles of 128 per slice
#define MAGIC 0x3C96A5E1u  // single-writer flag value (!= typical poison patterns)

// ctl line indices (128-B separated lines; word addr = line*32). NOTHING here
// needs pre-zeroing: every cell is single-writer MAGIC/value, read only after
// its flag — poison-proof without a memset dispatch.
#define PRD   0            // prodflag[1024]  : 1 writer, polled by 1 combiner thread each
#define CONS  1024         // consflag[8][128]: 1 writer, 1 poller each
#define TRIPF 2048         // tripflag[8][128]: 1 writer, <=1 poller each
#define TFLG  3072         // tailflag[128]   : 1 writer, 1 poller each
#define PART  3200         // per-line: word0=Hpart, word1=CEpart (single writer)

typedef float v4f __attribute__((ext_vector_type(4)));
typedef int   v8i __attribute__((ext_vector_type(8)));   // 32 fp8 (8 VGPRs)

// R1-R5 lesson ledger (what is cheap/expensive on MI355X cross-XCD):
//  - __threadfence (agent) = bulk buffer_wbl2/inv, ~0.35us each, serializes at
//    L2 -> 1024 of them = tens of us. NEVER use. (R4 A/B: +46us)
//  - relaxed-agent atomic store = write-through to MALL, cheap. (R5: passed)
//  - relaxed-agent atomic load  = read at MALL, cheap, coherent. (R5: passed)
//  - same-line agent requests serialize ~110ns -> keep pollers/line <= 8.
//  - __syncthreads() drains each wave's vmcnt -> write-through stores are
//    durable at MALL before a post-barrier flag store. (R5: passed)
//  - grid-wide sync of any flavor: 150+us. Use producer->consumer chaining.

__device__ __forceinline__ unsigned ld_flag(const unsigned* p) {
    return __hip_atomic_load(p, __ATOMIC_RELAXED, __HIP_MEMORY_SCOPE_AGENT);
}
__device__ __forceinline__ void st_flag(unsigned* p, unsigned v) {
    __hip_atomic_store(p, v, __ATOMIC_RELAXED, __HIP_MEMORY_SCOPE_AGENT);
}
__device__ __forceinline__ float ld_f32(const float* p) {
    return __hip_atomic_load(p, __ATOMIC_RELAXED, __HIP_MEMORY_SCOPE_AGENT);
}
__device__ __forceinline__ void st_f32(float* p, float v) {
    __hip_atomic_store(p, v, __ATOMIC_RELAXED, __HIP_MEMORY_SCOPE_AGENT);
}
__device__ __forceinline__ unsigned long long ld_u64(const void* p) {
    return __hip_atomic_load((const unsigned long long*)p, __ATOMIC_RELAXED,
                             __HIP_MEMORY_SCOPE_AGENT);
}

// ---------------------------------------------------------------- fused all:
// Single dispatch, grid 1024 x 256 (4 blocks/CU, LDS 40960 x 4 = 160 KiB/CU).
// phase P: block b preps rows b*8..b*8+7 -> write-through xq/sq/ce, prodflag.
// chain  : slice combiner (bx==0) polls 128 prodflags (parallel, 1/line),
//          broadcasts 128 consflags (1 poller/line).
// phase T: consumer (bx=b&127, by=b>>7) A-quant from x (host-coherent),
//          B reg-staged from xq via coherent 8B loads + ds_write (same XOR
//          swizzle), unchanged MFMA core + hardest-pos/neg epilogue.
// tail   : executor (by==bx&7) polls 7 tripflags, reduces 16 slices with all
//          4 waves, writes single-writer Hpart/CEpart + tailflag; block 0
//          polls 127 tailflags and runs Lambert-W. No atomics, no fences.
__global__ __launch_bounds__(256, 4) void k_all(const float* __restrict__ x,
                                                const int* __restrict__ tgt,
                                                unsigned* __restrict__ xqu,   // NB*32 uints
                                                float* __restrict__ sq,
                                                float* __restrict__ ce,
                                                unsigned* __restrict__ ctl,
                                                float* __restrict__ pmax,     // [16][NB]
                                                float* __restrict__ pmin,     // [16][NB]
                                                float* __restrict__ out) {
    __shared__ union {
        struct { unsigned char Bs[2][128 * 128]; float sqs[1024]; int tjs[1024]; } p2;
        struct { float vmx[4][64]; float vmn[4][64]; float fh[2], fc[2]; } p3;
    } sm;

    const int tid = threadIdx.x;
    const int b = (int)blockIdx.x;
    const int bx = b & 127;           // row block 0..127
    const int by = b >> 7;            // j-slice 0..7

    // ---------------- phase P: prep own 8 rows ----------------
    {
        int row = b * 8 + (tid >> 5);
        int l = tid & 31;
        float4 v = ((const float4*)(x + row * NC))[l];
        unsigned p = __builtin_amdgcn_cvt_pk_fp8_f32(v.x, v.y, 0, false);
        p = __builtin_amdgcn_cvt_pk_fp8_f32(v.z, v.w, p, true);
        __hip_atomic_store(xqu + row * 32 + l, p, __ATOMIC_RELAXED, __HIP_MEMORY_SCOPE_AGENT);

        float ss = fmaf(v.x, v.x, fmaf(v.y, v.y, fmaf(v.z, v.z, v.w * v.w)));
        float mx = fmaxf(fmaxf(v.x, v.y), fmaxf(v.z, v.w));
#pragma unroll
        for (int off = 16; off; off >>= 1) {
            ss += __shfl_xor(ss, off);
            mx = fmaxf(mx, __shfl_xor(mx, off));
        }
        float es = expf(v.x - mx) + expf(v.y - mx) + expf(v.z - mx) + expf(v.w - mx);
#pragma unroll
        for (int off = 16; off; off >>= 1) es += __shfl_xor(es, off);
        if (l == 0) {
            st_f32(sq + row, ss);
            st_f32(ce + row, mx + logf(es) - x[row * NC + tgt[row]]);
        }
    }
    __syncthreads();                  // drains all waves' write-through stores to MALL
    if (tid == 0) st_flag(ctl + (size_t)(PRD + b) * 32, MAGIC);

    // ---------------- chain: slice combiner (bx == 0) ----------------
    if (bx == 0) {
        if (tid < 128) {
            const unsigned* pf = ctl + (size_t)(PRD + by * 128 + tid) * 32;
            while (ld_flag(pf) != MAGIC) __builtin_amdgcn_s_sleep(8);
        }
        __syncthreads();              // all 128 producer flags observed
        if (tid < 128) st_flag(ctl + (size_t)(CONS + by * 128 + tid) * 32, MAGIC);
    }

    // ---------------- phase T: triplet GEMM ----------------
    const unsigned char* xq = (const unsigned char*)xqu;
    const int lane = tid & 63;
    const int w = tid >> 6;
    const int rh = w >> 1;            // row half (32 rows)
    const int ch = w & 1;             // col half (64 cols)
    const int i0 = bx * 64;
    const int jbase = by * 1024;
    const int m = lane & 15;
    const int quad = lane >> 4;

    // ---- A fragments quantized in-register from x (host data: coherent) ----
    v8i a[2];
#pragma unroll
    for (int tm = 0; tm < 2; ++tm) {
        int row = i0 + rh * 32 + tm * 16 + m;
        const float4* xr = (const float4*)(x + (size_t)row * NC + quad * 32);
        v8i af;
#pragma unroll
        for (int wd = 0; wd < 8; ++wd) {
            float4 f = xr[wd];
            unsigned p = __builtin_amdgcn_cvt_pk_fp8_f32(f.x, f.y, 0, false);
            p = __builtin_amdgcn_cvt_pk_fp8_f32(f.z, f.w, p, true);
            af[wd] = (int)p;
        }
        a[tm] = af;
    }

    // ---- anchor targets (host data: coherent) ----
    int ti[2][4];
#pragma unroll
    for (int tm = 0; tm < 2; ++tm)
#pragma unroll
        for (int r = 0; r < 4; ++r)
            ti[tm][r] = tgt[i0 + rh * 32 + tm * 16 + quad * 4 + r];

    // ---- wait for my B slice (private flag line, 1 poller) ----
    if (tid == 0) {
        const unsigned* cf = ctl + (size_t)(CONS + by * 128 + bx) * 32;
        while (ld_flag(cf) != MAGIC) __builtin_amdgcn_s_sleep(8);
    }
    __syncthreads();

    // ---- B staging: coherent reg-stage (8B agent loads) + swizzled ds_write.
    //      Identical addressing to the proven global_load_lds version:
    //      swizzled GLOBAL source, linear LDS chunk L*16.
    int4 breg[4];
    auto ldB = [&](int t) {
        int jn = jbase + t * 128;
#pragma unroll
        for (int c = 0; c < 4; ++c) {
            int L = w * 256 + c * 64 + lane;
            int col = L >> 3, cc = L & 7;
            const unsigned char* src = xq + (size_t)(jn + col) * 128 + ((cc ^ (col & 7)) << 4);
            unsigned long long lo = ld_u64(src);
            unsigned long long hi = ld_u64(src + 8);
            breg[c].x = (int)lo; breg[c].y = (int)(lo >> 32);
            breg[c].z = (int)hi; breg[c].w = (int)(hi >> 32);
        }
    };
    auto stB = [&](unsigned char* buf) {
#pragma unroll
        for (int c = 0; c < 4; ++c) {
            int L = w * 256 + c * 64 + lane;
            *(int4*)(buf + L * 16) = breg[c];
        }
    };

    ldB(0);
    stB(&sm.p2.Bs[0][0]);
    ldB(1);

    // ---- metadata: sq coherent reg-stage; tgt via global_load_lds (host) ----
    {
        unsigned long long s0 = ld_u64(sq + jbase + tid * 4);
        unsigned long long s1 = ld_u64(sq + jbase + tid * 4 + 2);
        int4 sv; sv.x = (int)s0; sv.y = (int)(s0 >> 32); sv.z = (int)s1; sv.w = (int)(s1 >> 32);
        *(int4*)(sm.p2.sqs + tid * 4) = sv;
        __builtin_amdgcn_global_load_lds(
            (const __attribute__((address_space(1))) unsigned*)((const unsigned*)(tgt + jbase) + tid * 4),
            (__attribute__((address_space(3))) unsigned*)(sm.p2.tjs + tid * 4),
            16, 0, 0);
    }

    float mp[2][4], mn[2][4];
#pragma unroll
    for (int tm = 0; tm < 2; ++tm)
#pragma unroll
        for (int r = 0; r < 4; ++r) { mp[tm][r] = -3.0e38f; mn[tm][r] = 3.0e38f; }

    __syncthreads();

#pragma unroll 2
    for (int jt = 0; jt < JPT; ++jt) {
        // regs hold tile jt+1: write it to the buffer last read at jt-1
        if (jt + 1 < JPT) stB(&sm.p2.Bs[(jt + 1) & 1][0]);
        if (jt + 2 < JPT) ldB(jt + 2);

        const unsigned char* Bcur = &sm.p2.Bs[jt & 1][0];

        float sqj[4]; int tj[4];
#pragma unroll
        for (int tn = 0; tn < 4; ++tn) {
            int cloc = jt * 128 + ch * 64 + tn * 16 + m;
            sqj[tn] = sm.p2.sqs[cloc];
            tj[tn] = sm.p2.tjs[cloc];
        }

        v8i bfr[4];
#pragma unroll
        for (int tn = 0; tn < 4; ++tn) {
            int col = ch * 64 + tn * 16 + m;
            int base = col * 128;
            int c0 = (((quad * 2) ^ (col & 7)) << 4);
            int c1 = (((quad * 2 + 1) ^ (col & 7)) << 4);
            *(int4*)&bfr[tn] = *(const int4*)(Bcur + base + c0);
            *((int4*)&bfr[tn] + 1) = *(const int4*)(Bcur + base + c1);
        }

        v4f acc[2][4];
        v4f z = {0.0f, 0.0f, 0.0f, 0.0f};
#pragma unroll
        for (int tm = 0; tm < 2; ++tm)
#pragma unroll
            for (int tn = 0; tn < 4; ++tn)
                acc[tm][tn] = __builtin_amdgcn_mfma_scale_f32_16x16x128_f8f6f4(
                    a[tm], bfr[tn], z, 0, 0, 0, 0x7f7f7f7f, 0, 0x7f7f7f7f);

#pragma unroll
        for (int tn = 0; tn < 4; ++tn) {
#pragma unroll
            for (int tm = 0; tm < 2; ++tm)
#pragma unroll
                for (int r = 0; r < 4; ++r) {
                    float v = fmaf(-2.0f, acc[tm][tn][r], sqj[tn]);
                    bool pos = (tj[tn] == ti[tm][r]);
                    mp[tm][r] = fmaxf(mp[tm][r], pos ? v : -3.0e38f);
                    mn[tm][r] = fminf(mn[tm][r], pos ? 3.0e38f : v);
                }
        }
        __syncthreads();
    }

    // ---- reduce across the 16 lanes sharing each output row ----
#pragma unroll
    for (int off = 1; off < 16; off <<= 1) {
#pragma unroll
        for (int tm = 0; tm < 2; ++tm)
#pragma unroll
            for (int r = 0; r < 4; ++r) {
                mp[tm][r] = fmaxf(mp[tm][r], __shfl_xor(mp[tm][r], off));
                mn[tm][r] = fminf(mn[tm][r], __shfl_xor(mn[tm][r], off));
            }
    }
    // ---- write-through partial stores ----
    if (m == 0) {
        int slice = by * 2 + ch;
        float* pm = pmax + (size_t)slice * NB + i0 + rh * 32;
        float* pn = pmin + (size_t)slice * NB + i0 + rh * 32;
#pragma unroll
        for (int tm = 0; tm < 2; ++tm)
#pragma unroll
            for (int r = 0; r < 4; ++r) {
                int rr = tm * 16 + quad * 4 + r;
                st_f32(pm + rr, mp[tm][r]);
                st_f32(pn + rr, mn[tm][r]);
            }
    }

    __syncthreads();                  // drain pm/pn write-through stores
    bool isExec = (by == (bx & 7));
    if (!isExec) {
        if (tid == 0) st_flag(ctl + (size_t)(TRIPF + by * 128 + bx) * 32, MAGIC);
        return;
    }

    // ---------------- tail executor (one per bx) ----------------
    if (w == 0 && lane < 8 && lane != by) {
        const unsigned* tf = ctl + (size_t)(TRIPF + lane * 128 + bx) * 32;
        while (ld_flag(tf) != MAGIC) __builtin_amdgcn_s_sleep(8);
    }
    __syncthreads();

    {   // stage 1: 4 waves x 4 slices each
        int lr = tid & 63, g = tid >> 6;
        int i = i0 + lr;
        float vmax = -3.0e38f, vmin = 3.0e38f;
#pragma unroll
        for (int k = 0; k < 4; ++k) {
            int s = g * 4 + k;
            vmax = fmaxf(vmax, ld_f32(pmax + (size_t)s * NB + i));
            vmin = fminf(vmin, ld_f32(pmin + (size_t)s * NB + i));
        }
        sm.p3.vmx[g][lr] = vmax;
        sm.p3.vmn[g][lr] = vmin;
    }
    __syncthreads();
    if (tid < 64) {                   // stage 2: hinge + CE over 64 rows
        int i = i0 + tid;
        float vmax = fmaxf(fmaxf(sm.p3.vmx[0][tid], sm.p3.vmx[1][tid]),
                           fmaxf(sm.p3.vmx[2][tid], sm.p3.vmx[3][tid]));
        float vmin = fminf(fminf(sm.p3.vmn[0][tid], sm.p3.vmn[1][tid]),
                           fminf(sm.p3.vmn[2][tid], sm.p3.vmn[3][tid]));
        float sqi = ld_f32(sq + i);
        float ap = sqrtf(fmaxf(fmaxf(sqi + vmax, 0.0f), 1e-12f));
        float an = sqrtf(fmaxf(fmaxf(sqi + vmin, 0.0f), 1e-12f));
        float hs = fmaxf(ap - an + 0.3f, 0.0f);
        float cs = ld_f32(ce + i);
#pragma unroll
        for (int off = 32; off; off >>= 1) {
            hs += __shfl_xor(hs, off);
            cs += __shfl_xor(cs, off);
        }
        if (tid == 0) {
            float* pl = (float*)(ctl + (size_t)(PART + bx) * 32);
            st_f32(pl + 0, hs);
            st_f32(pl + 1, cs);
            asm volatile("s_waitcnt vmcnt(0)" ::: "memory");   // parts durable
            st_flag(ctl + (size_t)(TFLG + bx) * 32, MAGIC);
        }
    }
    if (bx != 0) return;

    // ---------------- final block (b == 0): global sum + Lambert-W ----------------
    if (tid > 0 && tid < 128) {
        const unsigned* tf = ctl + (size_t)(TFLG + tid) * 32;
        while (ld_flag(tf) != MAGIC) __builtin_amdgcn_s_sleep(8);
    }
    __syncthreads();
    {
        float h = 0.0f, c2 = 0.0f;
        if (tid < 128) {
            const float* pl = (const float*)(ctl + (size_t)(PART + tid) * 32);
            h = ld_f32(pl + 0);
            c2 = ld_f32(pl + 1);
        }
#pragma unroll
        for (int off = 32; off; off >>= 1) {
            h += __shfl_xor(h, off);
            c2 += __shfl_xor(c2, off);
        }
        if ((tid & 63) == 0 && tid < 128) {
            sm.p3.fh[tid >> 6] = h;
            sm.p3.fc[tid >> 6] = c2;
        }
    }
    __syncthreads();
    if (tid == 0) {
        double H = (double)sm.p3.fh[0] + (double)sm.p3.fh[1];
        double Cs = (double)sm.p3.fc[0] + (double)sm.p3.fc[1];
        const double E = 2.71828182845904523536;
        const double TAU = log(128.0);
        const double LAMd = 0.25;
        double l = H / (double)NB;
        double cev = Cs / (double)NB;
        double y = 0.5 * fmax(-2.0 / E, (l - TAU) / LAMd);
        double p = sqrt(fmax(2.0 * (E * y + 1.0), 0.0));
        double wn = -1.0 + p - p * p / 3.0 + (11.0 / 72.0) * p * p * p;
        double wlw = (y < 0.0) ? wn : log1p(fmax(y, 0.0));
#pragma unroll
        for (int it = 0; it < 10; ++it) {
            double ew = exp(wlw);
            double f = wlw * ew - y;
            double wp1 = wlw + 1.0;
            wlw = wlw - f / (ew * wp1 - (wlw + 2.0) * f / (2.0 * wp1));
        }
        double sigma = exp(-wlw);
        double lg = log(sigma);
        double loss = (cev - TAU) * sigma + LAMd * lg * lg;
        out[0] = (float)(loss / (double)NB);
    }
}

// ---------------------------------------------------------------- launcher
extern "C" void kernel_launch(void* const* d_in, const int* in_sizes, int n_in,
                              void* d_out, int out_size, void* d_ws, size_t ws_size,
                              hipStream_t stream) {
    const float* x = (const float*)d_in[0];
    const int* tgt = (const int*)d_in[1];
    float* out = (float*)d_out;

    // ws: xq (1 MB) | sq (32 KB) | ce (32 KB) | ctl (3328 lines x 128 B = 416 KB)
    //   | pmax (512 KB) | pmin (512 KB).  No memset: all ctl cells are
    //   single-writer flag/value cells read only after their MAGIC flag.
    unsigned char* xq = (unsigned char*)d_ws;
    float* sq = (float*)(xq + (size_t)NB * 128);
    float* ce = sq + NB;
    unsigned* ctl = (unsigned*)(ce + NB);
    float* pmax = (float*)((unsigned char*)ctl + 3328 * 128);
    float* pmin = pmax + (size_t)16 * NB;

    k_all<<<dim3(1024), dim3(256), 0, stream>>>(x, tgt, (unsigned*)xq, sq, ce,
                                                ctl, pmax, pmin, out);
}